// Round 12
// baseline (241.384 us; speedup 1.0000x reference)
//
#include <hip/hip_runtime.h>
#include <math.h>

#define LN_EPS 1e-5f

typedef _Float16 f16;
typedef _Float16 f16x8 __attribute__((ext_vector_type(8)));
typedef _Float16 f16x2 __attribute__((ext_vector_type(2)));
typedef float f32x4 __attribute__((ext_vector_type(4)));

constexpr int DC = 16;
constexpr int K = 8192;
constexpr int NTOK = 16384;        // 8*2048
constexpr int D = 512;
constexpr float SCALE = 16384.f;   // 256 * 64, exact powers of 2
constexpr float EPS_S = LN_EPS * SCALE * SCALE;
// 2*eps margin for the approx (hi*hi+lo*lo) pass, scaled units:
// 2 * 2^-9 * ||h||(<=4) * 2||c||(<=2*10) * 16384 = 5120; +12% pad for fp32
// accumulation error -> 5760. ||c||^2 <= 100 holds for chi2_16 over 8192
// fixed draws with P(violation) ~ 1e-9.
constexpr float MARG2 = 5760.f;

static __device__ __forceinline__ f16x8 mk8(f16x2 a, f16x2 b, f16x2 c,
                                            f16x2 d) {
  union {
    f16x2 p[4];
    f16x8 v;
  } u;
  u.p[0] = a;
  u.p[1] = b;
  u.p[2] = c;
  u.p[3] = d;
  return u.v;
}

// hi = f32 masked to 11-bit mantissa (exact in f16; pkrtz exact on it),
// lo = residual (err <= 2^-10 * |v| on hi, residual subtraction exact).
static __device__ __forceinline__ void hilo2(float f0, float f1, f16x2& ph,
                                             f16x2& pl) {
  float h0 = __uint_as_float(__float_as_uint(f0) & 0xFFFFE000u);
  float h1 = __uint_as_float(__float_as_uint(f1) & 0xFFFFE000u);
  ph = __builtin_bit_cast(f16x2, __builtin_amdgcn_cvt_pkrtz(h0, h1));
  pl = __builtin_bit_cast(f16x2,
                          __builtin_amdgcn_cvt_pkrtz(f0 - h0, f1 - h1));
}

// ---------------------------------------------------------------------------
// prep: blocks [0,128): codebook -> cbA A-frags (x -128, hi/lo) + biased c2.
//       block 128: W -> wAf A-frags (x 64, hi/lo), 32 tiles.
// Frag per 16-row tile: lane l holds 8 halves, slots s=(l>>4)*8+p;
// s<16 -> hi(dim s), s>=16 -> lo(dim s-16). Rows = l&15.
// ---------------------------------------------------------------------------
__global__ __launch_bounds__(256) void prep(const float* __restrict__ cb,
                                            const float* __restrict__ wq,
                                            f16* __restrict__ cbA,
                                            float* __restrict__ c2s,
                                            f16* __restrict__ wAf) {
  const int tid = threadIdx.x;

  if (blockIdx.x == K / 64) {
#pragma unroll
    for (int i = 0; i < 8; ++i) {
      int slot = tid + 256 * i;
      int tile = slot >> 6;
      int l = slot & 63;
      int g = l >> 4;
      int col = l & 15;
      int doff = (g & 1) * 8;
      const float* wp = wq + (size_t)col * D + tile * 16 + doff;
      f32x4 u0 = *(const f32x4*)wp;
      f32x4 u1 = *(const f32x4*)(wp + 4);
      f16x2 ph[4], pl[4];
      hilo2(u0[0] * 64.f, u0[1] * 64.f, ph[0], pl[0]);
      hilo2(u0[2] * 64.f, u0[3] * 64.f, ph[1], pl[1]);
      hilo2(u1[0] * 64.f, u1[1] * 64.f, ph[2], pl[2]);
      hilo2(u1[2] * 64.f, u1[3] * 64.f, ph[3], pl[3]);
      f16x8 hi = mk8(ph[0], ph[1], ph[2], ph[3]);
      f16x8 lo = mk8(pl[0], pl[1], pl[2], pl[3]);
      *(f16x8*)(wAf + (size_t)slot * 8) = (g < 2) ? hi : lo;
    }
    return;
  }

  const int ti = tid >> 6;
  const int l = tid & 63;
  const int ct = blockIdx.x * 4 + ti;
  const int code = ct * 16 + (l & 15);
  const int g = l >> 4;

  const float* row = cb + (size_t)code * DC + (g & 1) * 8;
  f32x4 v0 = *(const f32x4*)row;
  f32x4 v1 = *(const f32x4*)(row + 4);
  f16x2 ph[4], pl[4];
  hilo2(v0[0] * -128.f, v0[1] * -128.f, ph[0], pl[0]);
  hilo2(v0[2] * -128.f, v0[3] * -128.f, ph[1], pl[1]);
  hilo2(v1[0] * -128.f, v1[1] * -128.f, ph[2], pl[2]);
  hilo2(v1[2] * -128.f, v1[3] * -128.f, ph[3], pl[3]);
  f16x8 hi = mk8(ph[0], ph[1], ph[2], ph[3]);
  f16x8 lo = mk8(pl[0], pl[1], pl[2], pl[3]);
  *(f16x8*)(cbA + ((size_t)ct * 64 + l) * 8) = (g < 2) ? hi : lo;

  if (g == 0) {
    const f32x4* rw = (const f32x4*)(cb + (size_t)code * DC);
    f32x4 a0 = rw[0], a1 = rw[1], a2 = rw[2], a3 = rw[3];
    float s = 0.f;
#pragma unroll
    for (int p = 0; p < 4; ++p)
      s += a0[p] * a0[p] + a1[p] * a1[p] + a2[p] * a2[p] + a3[p] * a3[p];
    c2s[code] = (s + 16.5f) * SCALE;   // +16.5 > h2=16 keeps dist > 0
  }
}

// ---------------------------------------------------------------------------
// fused: 256 blocks x 1024 thr. Phase A (proj+LN) identical to round 11.
// Phase B is now APPROX-FIRST: single MFMA per tile gives hi*hi+lo*lo+c2
// (error <= MARG2/2 scaled); per-(wave,128-code-group) mins -> LDS.
// Finalize: per token, m = min over 64 group-mins; exact-fp32-verify every
// group within m+MARG2 (k-ascending, typically exactly one), 8 codes/thread,
// strict-< lowest-k tie-break everywhere -> numpy argmin semantics.
// ---------------------------------------------------------------------------
__global__ __launch_bounds__(1024, 4) void fused(
    const float* __restrict__ x, const float* __restrict__ cb,
    const f16* __restrict__ cbA, const float* __restrict__ c2s,
    const f16* __restrict__ wAf, int* __restrict__ out) {
  __shared__ float comb[16 * 16 * 20];  // 20.5 KB [w][col][20]
  __shared__ float hsm[64 * 20];        // 5.1 KB  [tok][20]
  __shared__ float gm[16][4][64];       // 16 KB   [wave][group][token]

  const int tid = threadIdx.x;
  const int w = tid >> 6;
  const int lane = tid & 63;
  const int g = lane >> 4;
  const int col = lane & 15;
  const int doff = (g & 1) * 8;
  const int tb = blockIdx.x * 64;

  // ---------------- phase A: wave = (tile j, D-quarter dq) ----------------
  const int j = w & 3;
  const int dq = w >> 2;

  const float* xrow = x + (size_t)(tb + j * 16 + col) * D + dq * 128 + doff;
  f32x4 acc = {0.f, 0.f, 0.f, 0.f};
#pragma unroll
  for (int st = 0; st < 8; ++st) {
    f16x8 aw =
        *(const f16x8*)(wAf + ((size_t)(dq * 8 + st) * 64 + lane) * 8);
    f32x4 u0 = *(const f32x4*)(xrow + st * 16);
    f32x4 u1 = *(const f32x4*)(xrow + st * 16 + 4);
    f16x2 ph[4], pl[4];
    hilo2(u0[0] * 256.f, u0[1] * 256.f, ph[0], pl[0]);
    hilo2(u0[2] * 256.f, u0[3] * 256.f, ph[1], pl[1]);
    hilo2(u1[0] * 256.f, u1[1] * 256.f, ph[2], pl[2]);
    hilo2(u1[2] * 256.f, u1[3] * 256.f, ph[3], pl[3]);
    f16x8 bh = mk8(ph[0], ph[1], ph[2], ph[3]);
    f16x8 bl = mk8(pl[0], pl[1], pl[2], pl[3]);
    f16x8 b1 = (g < 2) ? bh : bl;
    f16x8 b2 = (g < 2) ? bl : bh;
    acc = __builtin_amdgcn_mfma_f32_16x16x32_f16(aw, b1, acc, 0, 0, 0);
    acc = __builtin_amdgcn_mfma_f32_16x16x32_f16(aw, b2, acc, 0, 0, 0);
  }
  *(f32x4*)&comb[(w * 16 + col) * 20 + g * 4] = acc;
  __syncthreads();

  // ---------------- LayerNorm (scaled values; exact ratio) ----------------
  {
    const int tokL = tid >> 4;           // 0..63
    const int cL = tid & 15;
    const int jL = tokL >> 4;            // tile
    const int colL = tokL & 15;
    float hv = 0.f;
#pragma unroll
    for (int dq2 = 0; dq2 < 4; ++dq2)
      hv += comb[((dq2 * 4 + jL) * 16 + colL) * 20 + cL];
    float s = hv;
    s += __shfl_xor(s, 1, 16);
    s += __shfl_xor(s, 2, 16);
    s += __shfl_xor(s, 4, 16);
    s += __shfl_xor(s, 8, 16);
    float mu = s * (1.f / 16.f);
    float diff = hv - mu;
    float v2 = diff * diff;
    v2 += __shfl_xor(v2, 1, 16);
    v2 += __shfl_xor(v2, 2, 16);
    v2 += __shfl_xor(v2, 4, 16);
    v2 += __shfl_xor(v2, 8, 16);
    float var = v2 * (1.f / 16.f);
    hsm[tokL * 20 + cL] = diff / sqrtf(var + EPS_S);  // unscaled LN'd h
  }
  __syncthreads();

  // ---------------- phase B: B frags (hi|lo only, no swapped pair) --------
  f16x8 b1[4];
#pragma unroll
  for (int jj = 0; jj < 4; ++jj) {
    const float* hp = &hsm[(jj * 16 + col) * 20 + doff];
    f32x4 u0 = *(const f32x4*)hp;
    f32x4 u1 = *(const f32x4*)(hp + 4);
    f16x2 ph[4], pl[4];
    hilo2(u0[0] * 256.f, u0[1] * 256.f, ph[0], pl[0]);
    hilo2(u0[2] * 256.f, u0[3] * 256.f, ph[1], pl[1]);
    hilo2(u1[0] * 256.f, u1[1] * 256.f, ph[2], pl[2]);
    hilo2(u1[2] * 256.f, u1[3] * 256.f, ph[3], pl[3]);
    f16x8 bh = mk8(ph[0], ph[1], ph[2], ph[3]);
    f16x8 bl = mk8(pl[0], pl[1], pl[2], pl[3]);
    b1[jj] = (g < 2) ? bh : bl;
  }

  // ---------------- phase B sweep: approx (1 MFMA/tile), group mins -------
  const int q = w;                       // slice [q*512, (q+1)*512)
  float gmin[4][4];                      // [jj][group]
#pragma unroll
  for (int jj = 0; jj < 4; ++jj)
#pragma unroll
    for (int gi = 0; gi < 4; ++gi) gmin[jj][gi] = 3.0e38f;

  const f16* pa = cbA + ((size_t)q * 32 * 64 + lane) * 8;
  const float* pc = c2s + q * 512 + g * 4;

#pragma unroll
  for (int gi = 0; gi < 4; ++gi) {
#pragma unroll
    for (int ti = 0; ti < 8; ++ti) {
      const int t = gi * 8 + ti;
      f16x8 a = *(const f16x8*)(pa + (size_t)t * 512);
      f32x4 c2v = *(const f32x4*)(pc + t * 16);
      __builtin_amdgcn_s_setprio(1);
      f32x4 d0 = __builtin_amdgcn_mfma_f32_16x16x32_f16(a, b1[0], c2v, 0, 0, 0);
      f32x4 d1 = __builtin_amdgcn_mfma_f32_16x16x32_f16(a, b1[1], c2v, 0, 0, 0);
      f32x4 d2 = __builtin_amdgcn_mfma_f32_16x16x32_f16(a, b1[2], c2v, 0, 0, 0);
      f32x4 d3 = __builtin_amdgcn_mfma_f32_16x16x32_f16(a, b1[3], c2v, 0, 0, 0);
      __builtin_amdgcn_s_setprio(0);
      gmin[0][gi] =
          fminf(gmin[0][gi], fminf(fminf(d0[0], d0[1]), fminf(d0[2], d0[3])));
      gmin[1][gi] =
          fminf(gmin[1][gi], fminf(fminf(d1[0], d1[1]), fminf(d1[2], d1[3])));
      gmin[2][gi] =
          fminf(gmin[2][gi], fminf(fminf(d2[0], d2[1]), fminf(d2[2], d2[3])));
      gmin[3][gi] =
          fminf(gmin[3][gi], fminf(fminf(d3[0], d3[1]), fminf(d3[2], d3[3])));
    }
  }

  // merge lane-groups (rows) per token; store per-(wave,group,token) min
#pragma unroll
  for (int jj = 0; jj < 4; ++jj) {
#pragma unroll
    for (int gi = 0; gi < 4; ++gi) {
      float v = gmin[jj][gi];
      v = fminf(v, __shfl_xor(v, 16));
      v = fminf(v, __shfl_xor(v, 32));
      if (lane < 16) gm[q][gi][jj * 16 + lane] = v;
    }
  }
  __syncthreads();

  // ---------------- finalize: margin-candidate exact verify ---------------
  {
    const int tok = tid >> 4;            // 0..63
    const int c = tid & 15;
    // m = min over all 64 group-mins (thread c covers wave q2=c)
    float m = fminf(fminf(gm[c][0][tok], gm[c][1][tok]),
                    fminf(gm[c][2][tok], gm[c][3][tok]));
    m = fminf(m, __shfl_xor(m, 1, 16));
    m = fminf(m, __shfl_xor(m, 2, 16));
    m = fminf(m, __shfl_xor(m, 4, 16));
    m = fminf(m, __shfl_xor(m, 8, 16));
    const float thr = m + MARG2;

    f32x4 h0 = *(const f32x4*)&hsm[tok * 20];
    f32x4 h1 = *(const f32x4*)&hsm[tok * 20 + 4];
    f32x4 h2 = *(const f32x4*)&hsm[tok * 20 + 8];
    f32x4 h3 = *(const f32x4*)&hsm[tok * 20 + 12];

    float bestd = 3.0e38f;
    int bestk = 0;
    // groups scanned in ascending-k order; exact fp32 verify of qualifiers
    for (int q2 = 0; q2 < 16; ++q2) {
#pragma unroll
      for (int gi = 0; gi < 4; ++gi) {
        if (gm[q2][gi][tok] <= thr) {
          const int kb = q2 * 512 + gi * 128 + c * 8;
#pragma unroll
          for (int r = 0; r < 8; ++r) {
            const int kk = kb + r;
            const f32x4* cr = (const f32x4*)(cb + (size_t)kk * DC);
            f32x4 c0 = cr[0], c1 = cr[1], c2r = cr[2], c3 = cr[3];
            float sd = 0.f;
#pragma unroll
            for (int p = 0; p < 4; ++p) {
              float e0 = h0[p] - c0[p];
              float e1 = h1[p] - c1[p];
              float e2f = h2[p] - c2r[p];
              float e3 = h3[p] - c3[p];
              sd = fmaf(e0, e0, sd);
              sd = fmaf(e1, e1, sd);
              sd = fmaf(e2f, e2f, sd);
              sd = fmaf(e3, e3, sd);
            }
            bool tk = sd < bestd;        // strict <: earliest k wins ties
            bestd = tk ? sd : bestd;
            bestk = tk ? kk : bestk;
          }
        }
      }
    }
    // merge the 16 threads of this token (lowest k on exact ties)
#pragma unroll
    for (int off = 1; off < 16; off <<= 1) {
      float od = __shfl_xor(bestd, off, 16);
      int ok = __shfl_xor(bestk, off, 16);
      bool tk = (od < bestd) || (od == bestd && ok < bestk);
      bestd = tk ? od : bestd;
      bestk = tk ? ok : bestk;
    }
    if (c == 0) out[tb + tok] = bestk;
  }
}

// ---------------------------------------------------------------------------
extern "C" void kernel_launch(void* const* d_in, const int* in_sizes, int n_in,
                              void* d_out, int out_size, void* d_ws,
                              size_t ws_size, hipStream_t stream) {
  const float* x = (const float*)d_in[0];    // (8,2048,512)
  const float* w = (const float*)d_in[1];    // (16,512)
  const float* cb = (const float*)d_in[2];   // (8192,16)

  f16* cbA = (f16*)d_ws;                        // 512 KB
  float* c2s = (float*)(cbA + (size_t)K * 32);  // 32 KB
  f16* wAf = (f16*)(c2s + K);                   // 32 KB

  prep<<<K / 64 + 1, 256, 0, stream>>>(cb, w, cbA, c2s, wAf);
  fused<<<NTOK / 64, 1024, 0, stream>>>(x, cb, cbA, c2s, wAf, (int*)d_out);
}

// Round 13
// 39.575 us; speedup vs baseline: 6.0993x; 6.0993x over previous
//
#include <hip/hip_runtime.h>
#include <math.h>

#define LN_EPS 1e-5f

typedef _Float16 f16;
typedef _Float16 f16x8 __attribute__((ext_vector_type(8)));
typedef _Float16 f16x2 __attribute__((ext_vector_type(2)));
typedef float f32x4 __attribute__((ext_vector_type(4)));

constexpr int DC = 16;
constexpr int K = 8192;
constexpr int NTOK = 16384;        // 8*2048
constexpr int D = 512;
constexpr float SCALE = 16384.f;   // 256 * 64, exact powers of 2
constexpr float EPS_S = LN_EPS * SCALE * SCALE;

static __device__ __forceinline__ f16x8 mk8(f16x2 a, f16x2 b, f16x2 c,
                                            f16x2 d) {
  union {
    f16x2 p[4];
    f16x8 v;
  } u;
  u.p[0] = a;
  u.p[1] = b;
  u.p[2] = c;
  u.p[3] = d;
  return u.v;
}

// hi = f32 masked to 11-bit mantissa (exact in f16; pkrtz exact on it),
// lo = residual (err <= 2^-23 * |v| total).
static __device__ __forceinline__ void hilo2(float f0, float f1, f16x2& ph,
                                             f16x2& pl) {
  float h0 = __uint_as_float(__float_as_uint(f0) & 0xFFFFE000u);
  float h1 = __uint_as_float(__float_as_uint(f1) & 0xFFFFE000u);
  ph = __builtin_bit_cast(f16x2, __builtin_amdgcn_cvt_pkrtz(h0, h1));
  pl = __builtin_bit_cast(f16x2,
                          __builtin_amdgcn_cvt_pkrtz(f0 - h0, f1 - h1));
}

// ---------------------------------------------------------------------------
// prep: blocks [0,128): codebook -> cbA A-frags (x -128, hi/lo) + biased c2.
//       block 128: W -> wAf A-frags (x 64, hi/lo), 32 tiles.
// Frag per 16-row tile: lane l holds 8 halves, slots s=(l>>4)*8+p;
// s<16 -> hi(dim s), s>=16 -> lo(dim s-16). Rows = l&15.
// ---------------------------------------------------------------------------
__global__ __launch_bounds__(256) void prep(const float* __restrict__ cb,
                                            const float* __restrict__ wq,
                                            f16* __restrict__ cbA,
                                            float* __restrict__ c2s,
                                            f16* __restrict__ wAf) {
  const int tid = threadIdx.x;

  if (blockIdx.x == K / 64) {
#pragma unroll
    for (int i = 0; i < 8; ++i) {
      int slot = tid + 256 * i;
      int tile = slot >> 6;
      int l = slot & 63;
      int g = l >> 4;
      int col = l & 15;
      int doff = (g & 1) * 8;
      const float* wp = wq + (size_t)col * D + tile * 16 + doff;
      f32x4 u0 = *(const f32x4*)wp;
      f32x4 u1 = *(const f32x4*)(wp + 4);
      f16x2 ph[4], pl[4];
      hilo2(u0[0] * 64.f, u0[1] * 64.f, ph[0], pl[0]);
      hilo2(u0[2] * 64.f, u0[3] * 64.f, ph[1], pl[1]);
      hilo2(u1[0] * 64.f, u1[1] * 64.f, ph[2], pl[2]);
      hilo2(u1[2] * 64.f, u1[3] * 64.f, ph[3], pl[3]);
      f16x8 hi = mk8(ph[0], ph[1], ph[2], ph[3]);
      f16x8 lo = mk8(pl[0], pl[1], pl[2], pl[3]);
      *(f16x8*)(wAf + (size_t)slot * 8) = (g < 2) ? hi : lo;
    }
    return;
  }

  const int ti = tid >> 6;
  const int l = tid & 63;
  const int ct = blockIdx.x * 4 + ti;
  const int code = ct * 16 + (l & 15);
  const int g = l >> 4;

  const float* row = cb + (size_t)code * DC + (g & 1) * 8;
  f32x4 v0 = *(const f32x4*)row;
  f32x4 v1 = *(const f32x4*)(row + 4);
  f16x2 ph[4], pl[4];
  hilo2(v0[0] * -128.f, v0[1] * -128.f, ph[0], pl[0]);
  hilo2(v0[2] * -128.f, v0[3] * -128.f, ph[1], pl[1]);
  hilo2(v1[0] * -128.f, v1[1] * -128.f, ph[2], pl[2]);
  hilo2(v1[2] * -128.f, v1[3] * -128.f, ph[3], pl[3]);
  f16x8 hi = mk8(ph[0], ph[1], ph[2], ph[3]);
  f16x8 lo = mk8(pl[0], pl[1], pl[2], pl[3]);
  *(f16x8*)(cbA + ((size_t)ct * 64 + l) * 8) = (g < 2) ? hi : lo;

  if (g == 0) {
    const f32x4* rw = (const f32x4*)(cb + (size_t)code * DC);
    f32x4 a0 = rw[0], a1 = rw[1], a2 = rw[2], a3 = rw[3];
    float s = 0.f;
#pragma unroll
    for (int p = 0; p < 4; ++p)
      s += a0[p] * a0[p] + a1[p] * a1[p] + a2[p] * a2[p] + a3[p] * a3[p];
    c2s[code] = (s + 16.5f) * SCALE;   // +16.5 > h2=16 keeps dist > 0
  }
}

// ---------------------------------------------------------------------------
// fused: 256 blocks x 1024 thr, __launch_bounds__(1024,4). Block owns 64
// tokens. (Round-11 structure, reverted verbatim after the round-12
// approx-first rewrite spilled to scratch: 388 MB WRITE_SIZE, 6x slower.)
// Phase A: wave (j=w&3 tile, dq=w>>2 D-quarter, 8 K-steps): x direct from
//   global, W frags preloaded; combine 4 partials via LDS; LN width-16 shfl.
// Phase B: wave w sweeps its 512-code slice (32 tiles) for 4 token-tiles;
//   tag-free running min + per-8-tile group tag; setprio around MFMA cluster.
// Merge 16 wave-candidates; winning 32-code group disambiguated by exact
// fp32 recompute (16 threads/token). Straight to d_out.
// ---------------------------------------------------------------------------
__global__ __launch_bounds__(1024, 4) void fused(
    const float* __restrict__ x, const float* __restrict__ cb,
    const f16* __restrict__ cbA, const float* __restrict__ c2s,
    const f16* __restrict__ wAf, int* __restrict__ out) {
  __shared__ float comb[16 * 16 * 20];  // 20.5 KB [w][col][20]
  __shared__ float hsm[64 * 20];        // 5.1 KB  [tok][20]
  __shared__ float fin_d[16][64];       // 4 KB
  __shared__ int fin_t[16][64];         // 4 KB

  const int tid = threadIdx.x;
  const int w = tid >> 6;
  const int lane = tid & 63;
  const int g = lane >> 4;
  const int col = lane & 15;
  const int doff = (g & 1) * 8;
  const int tb = blockIdx.x * 64;

  // ---------------- phase A: wave = (tile j, D-quarter dq) ----------------
  const int j = w & 3;
  const int dq = w >> 2;

  const float* xrow = x + (size_t)(tb + j * 16 + col) * D + dq * 128 + doff;
  f32x4 acc = {0.f, 0.f, 0.f, 0.f};
#pragma unroll
  for (int st = 0; st < 8; ++st) {
    f16x8 aw =
        *(const f16x8*)(wAf + ((size_t)(dq * 8 + st) * 64 + lane) * 8);
    f32x4 u0 = *(const f32x4*)(xrow + st * 16);
    f32x4 u1 = *(const f32x4*)(xrow + st * 16 + 4);
    f16x2 ph[4], pl[4];
    hilo2(u0[0] * 256.f, u0[1] * 256.f, ph[0], pl[0]);
    hilo2(u0[2] * 256.f, u0[3] * 256.f, ph[1], pl[1]);
    hilo2(u1[0] * 256.f, u1[1] * 256.f, ph[2], pl[2]);
    hilo2(u1[2] * 256.f, u1[3] * 256.f, ph[3], pl[3]);
    f16x8 bh = mk8(ph[0], ph[1], ph[2], ph[3]);
    f16x8 bl = mk8(pl[0], pl[1], pl[2], pl[3]);
    f16x8 b1 = (g < 2) ? bh : bl;
    f16x8 b2 = (g < 2) ? bl : bh;
    acc = __builtin_amdgcn_mfma_f32_16x16x32_f16(aw, b1, acc, 0, 0, 0);
    acc = __builtin_amdgcn_mfma_f32_16x16x32_f16(aw, b2, acc, 0, 0, 0);
  }
  *(f32x4*)&comb[(w * 16 + col) * 20 + g * 4] = acc;
  __syncthreads();

  // ---------------- LayerNorm (scaled values; exact ratio) ----------------
  {
    const int tokL = tid >> 4;           // 0..63
    const int cL = tid & 15;
    const int jL = tokL >> 4;            // tile
    const int colL = tokL & 15;
    float hv = 0.f;
#pragma unroll
    for (int dq2 = 0; dq2 < 4; ++dq2)
      hv += comb[((dq2 * 4 + jL) * 16 + colL) * 20 + cL];
    float s = hv;
    s += __shfl_xor(s, 1, 16);
    s += __shfl_xor(s, 2, 16);
    s += __shfl_xor(s, 4, 16);
    s += __shfl_xor(s, 8, 16);
    float mu = s * (1.f / 16.f);
    float diff = hv - mu;
    float v2 = diff * diff;
    v2 += __shfl_xor(v2, 1, 16);
    v2 += __shfl_xor(v2, 2, 16);
    v2 += __shfl_xor(v2, 4, 16);
    v2 += __shfl_xor(v2, 8, 16);
    float var = v2 * (1.f / 16.f);
    hsm[tokL * 20 + cL] = diff / sqrtf(var + EPS_S);  // unscaled LN'd h
  }
  __syncthreads();

  // ---------------- phase B: B frags for the 4 token-tiles ----------------
  f16x8 b1[4], b2[4];
#pragma unroll
  for (int jj = 0; jj < 4; ++jj) {
    const float* hp = &hsm[(jj * 16 + col) * 20 + doff];
    f32x4 u0 = *(const f32x4*)hp;
    f32x4 u1 = *(const f32x4*)(hp + 4);
    f16x2 ph[4], pl[4];
    hilo2(u0[0] * 256.f, u0[1] * 256.f, ph[0], pl[0]);
    hilo2(u0[2] * 256.f, u0[3] * 256.f, ph[1], pl[1]);
    hilo2(u1[0] * 256.f, u1[1] * 256.f, ph[2], pl[2]);
    hilo2(u1[2] * 256.f, u1[3] * 256.f, ph[3], pl[3]);
    f16x8 bh = mk8(ph[0], ph[1], ph[2], ph[3]);
    f16x8 bl = mk8(pl[0], pl[1], pl[2], pl[3]);
    b1[jj] = (g < 2) ? bh : bl;
    b2[jj] = (g < 2) ? bl : bh;
  }

  // ---------------- phase B sweep: 32 tiles, JT=4, tag-free min -----------
  const int q = w;                       // slice [q*512, (q+1)*512)
  float best[4] = {3.0e38f, 3.0e38f, 3.0e38f, 3.0e38f};
  int grp[4] = {0, 0, 0, 0};
  const f16* pa = cbA + ((size_t)q * 32 * 64 + lane) * 8;
  const float* pc = c2s + q * 512 + g * 4;

  for (int gi = 0; gi < 4; ++gi) {
    float sb0 = best[0], sb1 = best[1], sb2 = best[2], sb3 = best[3];
#pragma unroll
    for (int ti = 0; ti < 8; ++ti) {
      int t = gi * 8 + ti;
      f16x8 a = *(const f16x8*)(pa + (size_t)t * 512);
      f32x4 c2v = *(const f32x4*)(pc + t * 16);
      __builtin_amdgcn_s_setprio(1);
      f32x4 d0 = __builtin_amdgcn_mfma_f32_16x16x32_f16(a, b1[0], c2v, 0, 0, 0);
      d0 = __builtin_amdgcn_mfma_f32_16x16x32_f16(a, b2[0], d0, 0, 0, 0);
      f32x4 d1 = __builtin_amdgcn_mfma_f32_16x16x32_f16(a, b1[1], c2v, 0, 0, 0);
      d1 = __builtin_amdgcn_mfma_f32_16x16x32_f16(a, b2[1], d1, 0, 0, 0);
      f32x4 d2 = __builtin_amdgcn_mfma_f32_16x16x32_f16(a, b1[2], c2v, 0, 0, 0);
      d2 = __builtin_amdgcn_mfma_f32_16x16x32_f16(a, b2[2], d2, 0, 0, 0);
      f32x4 d3 = __builtin_amdgcn_mfma_f32_16x16x32_f16(a, b1[3], c2v, 0, 0, 0);
      d3 = __builtin_amdgcn_mfma_f32_16x16x32_f16(a, b2[3], d3, 0, 0, 0);
      __builtin_amdgcn_s_setprio(0);
      best[0] = fminf(best[0], fminf(fminf(d0[0], d0[1]), fminf(d0[2], d0[3])));
      best[1] = fminf(best[1], fminf(fminf(d1[0], d1[1]), fminf(d1[2], d1[3])));
      best[2] = fminf(best[2], fminf(fminf(d2[0], d2[1]), fminf(d2[2], d2[3])));
      best[3] = fminf(best[3], fminf(fminf(d3[0], d3[1]), fminf(d3[2], d3[3])));
    }
    grp[0] = (best[0] < sb0) ? gi : grp[0];  // strict <: earliest group wins
    grp[1] = (best[1] < sb1) ? gi : grp[1];
    grp[2] = (best[2] < sb2) ? gi : grp[2];
    grp[3] = (best[3] < sb3) ? gi : grp[3];
  }

  // merge lane-groups per token-tile; tag = grp*4+g (grp major == k major)
#pragma unroll
  for (int jj = 0; jj < 4; ++jj) {
    float d = best[jj];
    int tg = grp[jj] * 4 + g;
#pragma unroll
    for (int off = 16; off <= 32; off <<= 1) {
      float od = __shfl_xor(d, off);
      int ot = __shfl_xor(tg, off);
      bool tk = (od < d) || (od == d && ot < tg);
      d = tk ? od : d;
      tg = tk ? ot : tg;
    }
    if (lane < 16) {
      fin_d[q][jj * 16 + lane] = d;
      fin_t[q][jj * 16 + lane] = tg;
    }
  }
  __syncthreads();

  // ---------------- finalize: 16 threads/token, 32-code exact verify ------
  {
    const int tok = tid >> 4;            // 0..63
    const int c = tid & 15;
    float bd = fin_d[0][tok];
    int btag = fin_t[0][tok];
    int bq = 0;
#pragma unroll
    for (int q2 = 1; q2 < 16; ++q2) {
      float d2 = fin_d[q2][tok];
      int t2 = fin_t[q2][tok];
      bool tk = d2 < bd;                 // ascending q: strict <
      bd = tk ? d2 : bd;
      btag = tk ? t2 : btag;
      bq = tk ? q2 : bq;
    }
    const int kb = bq * 512 + (btag >> 2) * 128 + (btag & 3) * 4;

    f32x4 h0 = *(const f32x4*)&hsm[tok * 20];
    f32x4 h1 = *(const f32x4*)&hsm[tok * 20 + 4];
    f32x4 h2 = *(const f32x4*)&hsm[tok * 20 + 8];
    f32x4 h3 = *(const f32x4*)&hsm[tok * 20 + 12];

    float bestd = 3.0e38f;
    int bestk = kb;
#pragma unroll
    for (int e2 = 0; e2 < 2; ++e2) {
      int e = c * 2 + e2;                // e ascending == k ascending
      int kk = kb + (e >> 2) * 16 + (e & 3);
      const f32x4* cr = (const f32x4*)(cb + (size_t)kk * DC);
      f32x4 c0 = cr[0], c1 = cr[1], c2r = cr[2], c3 = cr[3];
      float sd = 0.f;
#pragma unroll
      for (int p = 0; p < 4; ++p) {
        float e0 = h0[p] - c0[p];
        float e1 = h1[p] - c1[p];
        float e2f = h2[p] - c2r[p];
        float e3 = h3[p] - c3[p];
        sd = fmaf(e0, e0, sd);
        sd = fmaf(e1, e1, sd);
        sd = fmaf(e2f, e2f, sd);
        sd = fmaf(e3, e3, sd);
      }
      bool tk = sd < bestd;
      bestd = tk ? sd : bestd;
      bestk = tk ? kk : bestk;
    }
#pragma unroll
    for (int off = 1; off < 16; off <<= 1) {
      float od = __shfl_xor(bestd, off, 16);
      int ok = __shfl_xor(bestk, off, 16);
      bool tk = (od < bestd) || (od == bestd && ok < bestk);
      bestd = tk ? od : bestd;
      bestk = tk ? ok : bestk;
    }
    if (c == 0) out[tb + tok] = bestk;
  }
}

// ---------------------------------------------------------------------------
extern "C" void kernel_launch(void* const* d_in, const int* in_sizes, int n_in,
                              void* d_out, int out_size, void* d_ws,
                              size_t ws_size, hipStream_t stream) {
  const float* x = (const float*)d_in[0];    // (8,2048,512)
  const float* w = (const float*)d_in[1];    // (16,512)
  const float* cb = (const float*)d_in[2];   // (8192,16)

  f16* cbA = (f16*)d_ws;                        // 512 KB
  float* c2s = (float*)(cbA + (size_t)K * 32);  // 32 KB
  f16* wAf = (f16*)(c2s + K);                   // 32 KB

  prep<<<K / 64 + 1, 256, 0, stream>>>(cb, w, cbA, c2s, wAf);
  fused<<<NTOK / 64, 1024, 0, stream>>>(x, cb, cbA, c2s, wAf, (int*)d_out);
}